// Round 7
// baseline (1479.461 us; speedup 1.0000x reference)
//
#include <hip/hip_runtime.h>
#include <hip/hip_fp16.h>
#include <math.h>

#define N_NODES 100000
#define N_EDGES 3200000
#define F_IN    128
#define F_HID   32
#define F_OUT   40
#define BIN_SHIFT 7
#define BIN_NODES 128
#define NBINS   ((N_NODES + BIN_NODES - 1) >> BIN_SHIFT)   // 782 bins of 128 nodes
#define EPB     4096
#define NBLK    ((N_EDGES + EPB - 1) / EPB)                // 782 partition blocks

// ---------------------------------------------------------------------------
// GEMM1: h1h[N,32] = fp16(x[N,128] @ W1[128,32])
// ---------------------------------------------------------------------------
__global__ __launch_bounds__(256) void gemm1_kernel(const float* __restrict__ x,
                                                    const float* __restrict__ W,
                                                    __half* __restrict__ h1h) {
    __shared__ float Ws[F_IN * F_HID];     // 16 KB
    __shared__ float Xs[32][F_IN + 4];
    const int tid  = threadIdx.x;
    const int row0 = blockIdx.x * 32;

    for (int i = tid; i < (F_IN * F_HID) / 4; i += 256)
        ((float4*)Ws)[i] = ((const float4*)W)[i];

    for (int i = tid; i < 1024; i += 256) {
        int r = i >> 5;
        int c = i & 31;
        ((float4*)&Xs[r][0])[c] = ((const float4*)x)[(size_t)(row0 + r) * (F_IN / 4) + c];
    }
    __syncthreads();

    const int r  = tid >> 3;
    const int c0 = (tid & 7) * 4;
    float a0 = 0.f, a1 = 0.f, a2 = 0.f, a3 = 0.f;
    for (int k = 0; k < F_IN; ++k) {
        const float xv = Xs[r][k];
        const float* wrow = &Ws[k * F_HID + c0];
        a0 += xv * wrow[0];
        a1 += xv * wrow[1];
        a2 += xv * wrow[2];
        a3 += xv * wrow[3];
    }
    const int row = row0 + r;   // grid exact: 3125*32 == N_NODES
    __half2* o = (__half2*)(h1h + (size_t)row * F_HID + c0);
    o[0] = __floats2half2_rn(a0, a1);
    o[1] = __floats2half2_rn(a2, a3);
}

// ---------------------------------------------------------------------------
// Stage 1: per-block bin histogram (LDS), coalesced dump to gcnt[blk][bin].
// 4-deep preload breaks load->atomic dependency stalls.
// ---------------------------------------------------------------------------
__global__ __launch_bounds__(256) void binhistA_kernel(const int* __restrict__ ei,
                                                       int* __restrict__ gcnt) {
    __shared__ int lh[NBINS];
    const int tid = threadIdx.x;
    const int e0  = blockIdx.x * EPB;
    for (int i = tid; i < NBINS; i += 256) lh[i] = 0;
    __syncthreads();

    for (int base = 0; base < EPB; base += 1024) {
        int d0 = -1, d1 = -1, d2 = -1, d3 = -1;
        const int e = e0 + base + tid;
        if (e < N_EDGES)            d0 = ei[N_EDGES + e] >> BIN_SHIFT;
        if (e + 256 < N_EDGES)      d1 = ei[N_EDGES + e + 256] >> BIN_SHIFT;
        if (e + 512 < N_EDGES)      d2 = ei[N_EDGES + e + 512] >> BIN_SHIFT;
        if (e + 768 < N_EDGES)      d3 = ei[N_EDGES + e + 768] >> BIN_SHIFT;
        if (d0 >= 0) atomicAdd(&lh[d0], 1);
        if (d1 >= 0) atomicAdd(&lh[d1], 1);
        if (d2 >= 0) atomicAdd(&lh[d2], 1);
        if (d3 >= 0) atomicAdd(&lh[d3], 1);
    }
    __syncthreads();
    for (int b = tid; b < NBINS; b += 256)
        gcnt[(size_t)blockIdx.x * NBINS + b] = lh[b];
}

// ---------------------------------------------------------------------------
// Stage 2: per-bin column scan over blocks -> pbase[blk][bin] (exclusive,
// relative to bin start) and bintot[bin]. One block per bin.
// ---------------------------------------------------------------------------
__global__ __launch_bounds__(256) void colscan_kernel(const int* __restrict__ gcnt,
                                                      int* __restrict__ pbase,
                                                      int* __restrict__ bintot) {
    __shared__ int s[256];
    __shared__ int carry;
    const int b   = blockIdx.x;
    const int tid = threadIdx.x;
    if (tid == 0) carry = 0;
    __syncthreads();
    for (int c = 0; c < NBLK; c += 256) {
        const int blk = c + tid;
        const int v = (blk < NBLK) ? gcnt[(size_t)blk * NBINS + b] : 0;
        s[tid] = v;
        __syncthreads();
        for (int off = 1; off < 256; off <<= 1) {
            int u = (tid >= off) ? s[tid - off] : 0;
            __syncthreads();
            s[tid] += u;
            __syncthreads();
        }
        if (blk < NBLK) pbase[(size_t)blk * NBINS + b] = carry + s[tid] - v;
        __syncthreads();
        if (tid == 255) carry += s[255];
        __syncthreads();
    }
    if (tid == 0) bintot[b] = carry;
}

// ---------------------------------------------------------------------------
// Stage 3: exclusive scan over 782 bin totals -> binbase[0..NBINS].
// ---------------------------------------------------------------------------
__global__ __launch_bounds__(1024) void binscan_kernel(const int* __restrict__ bintot,
                                                       int* __restrict__ binbase) {
    __shared__ int s[1024];
    const int t = threadIdx.x;
    const int v = (t < NBINS) ? bintot[t] : 0;
    s[t] = v;
    __syncthreads();
    for (int off = 1; off < 1024; off <<= 1) {
        int u = (t >= off) ? s[t - off] : 0;
        __syncthreads();
        s[t] += u;
        __syncthreads();
    }
    if (t <= NBINS) binbase[t] = s[t] - v;
}

// ---------------------------------------------------------------------------
// Stage 4: place. Cursors = binbase + pbase loaded into LDS (no global
// atomics); 4-deep preloaded loop; staged entry:
//   .x = src(17b) | dst_low7 << 17, .y = weight fp32 bits.
// ---------------------------------------------------------------------------
__global__ __launch_bounds__(256) void placeA_kernel(const int* __restrict__ ei,
                                                     const float* __restrict__ ew,
                                                     const int* __restrict__ binbase,
                                                     const int* __restrict__ pbase,
                                                     int2* __restrict__ stg) {
    __shared__ int lcur[NBINS];
    const int tid = threadIdx.x;
    const int blk = blockIdx.x;
    const int e0  = blk * EPB;
    for (int b = tid; b < NBINS; b += 256)
        lcur[b] = binbase[b] + pbase[(size_t)blk * NBINS + b];
    __syncthreads();

    for (int base = 0; base < EPB; base += 1024) {
        int s0 = 0, s1 = 0, s2 = 0, s3 = 0;
        int d0 = -1, d1 = -1, d2 = -1, d3 = -1;
        float w0 = 0.f, w1 = 0.f, w2 = 0.f, w3 = 0.f;
        const int e = e0 + base + tid;
        if (e < N_EDGES)       { s0 = ei[e];       d0 = ei[N_EDGES + e];       w0 = ew[e]; }
        if (e + 256 < N_EDGES) { s1 = ei[e + 256]; d1 = ei[N_EDGES + e + 256]; w1 = ew[e + 256]; }
        if (e + 512 < N_EDGES) { s2 = ei[e + 512]; d2 = ei[N_EDGES + e + 512]; w2 = ew[e + 512]; }
        if (e + 768 < N_EDGES) { s3 = ei[e + 768]; d3 = ei[N_EDGES + e + 768]; w3 = ew[e + 768]; }
        if (d0 >= 0) {
            const int pos = atomicAdd(&lcur[d0 >> BIN_SHIFT], 1);
            stg[pos] = make_int2(s0 | ((d0 & 127) << 17), __float_as_int(w0));
        }
        if (d1 >= 0) {
            const int pos = atomicAdd(&lcur[d1 >> BIN_SHIFT], 1);
            stg[pos] = make_int2(s1 | ((d1 & 127) << 17), __float_as_int(w1));
        }
        if (d2 >= 0) {
            const int pos = atomicAdd(&lcur[d2 >> BIN_SHIFT], 1);
            stg[pos] = make_int2(s2 | ((d2 & 127) << 17), __float_as_int(w2));
        }
        if (d3 >= 0) {
            const int pos = atomicAdd(&lcur[d3 >> BIN_SHIFT], 1);
            stg[pos] = make_int2(s3 | ((d3 & 127) << 17), __float_as_int(w3));
        }
    }
}

// ---------------------------------------------------------------------------
// Shared edge-accumulate body: 8 lanes/edge, uint2 (4-feat) fragment each,
// ds_add_f32 into acc[dlow*33 + q*4 + i] (stride-33 spreads banks).
// ---------------------------------------------------------------------------
#define AGG_EDGE(P, RV)                                                         \
    {                                                                           \
        const float w = __int_as_float((P).y);                                  \
        float* a = &acc[(((P).x >> 17) & 127) * 33 + q4];                       \
        float2 v0 = __half22float2(*(const __half2*)&(RV).x);                   \
        float2 v1 = __half22float2(*(const __half2*)&(RV).y);                   \
        atomicAdd(a + 0, v0.x * w);                                             \
        atomicAdd(a + 1, v0.y * w);                                             \
        atomicAdd(a + 2, v1.x * w);                                             \
        atomicAdd(a + 3, v1.y * w);                                             \
    }

// ---------------------------------------------------------------------------
// Aggregation 1 (+bias1+ReLU): one block per bin; LDS fp32 accumulator
// acc[128][33]; epilogue packs fp16 rows of rh.
// ---------------------------------------------------------------------------
__global__ __launch_bounds__(256) void agg1_kernel(const int* __restrict__ binbase,
                                                   const int2* __restrict__ stg,
                                                   const __half* __restrict__ h1h,
                                                   const float* __restrict__ b1,
                                                   __half* __restrict__ rh) {
    __shared__ float acc[BIN_NODES * 33];       // 16.9 KB
    const int tid = threadIdx.x;
    const int b   = blockIdx.x;
    for (int i = tid; i < BIN_NODES * 33; i += 256) acc[i] = 0.f;
    __syncthreads();

    const int start = binbase[b], end = binbase[b + 1];
    const int q  = tid & 7;
    const int q4 = q * 4;
    const unsigned q8 = q * 8;
    const char* tbl = (const char*)h1h;

    for (int j0 = start; j0 < end; j0 += 64) {
        const int j1 = j0 + (tid >> 3);
        const int j2 = j1 + 32;
        const bool v1 = j1 < end, v2 = j2 < end;
        int2 p1 = make_int2(0, 0), p2 = make_int2(0, 0);
        uint2 r1 = make_uint2(0, 0), r2 = make_uint2(0, 0);
        if (v1) { p1 = stg[j1]; r1 = *(const uint2*)(tbl + ((unsigned)(p1.x & 0x1FFFF) << 6) + q8); }
        if (v2) { p2 = stg[j2]; r2 = *(const uint2*)(tbl + ((unsigned)(p2.x & 0x1FFFF) << 6) + q8); }
        if (v1) AGG_EDGE(p1, r1);
        if (v2) AGG_EDGE(p2, r2);
    }
    __syncthreads();

    // epilogue: thread t -> node t>>1, feature half (t&1)*16
    const int nn = tid >> 1;
    const int f0 = (tid & 1) * 16;
    const int node = (b << BIN_SHIFT) + nn;
    if (node < N_NODES) {
        uint4 o[2];
        __half2* oh = (__half2*)o;
        #pragma unroll
        for (int i = 0; i < 8; ++i) {
            const int f = f0 + i * 2;
            const float v0 = fmaxf(acc[nn * 33 + f]     + b1[f],     0.f);
            const float v1 = fmaxf(acc[nn * 33 + f + 1] + b1[f + 1], 0.f);
            oh[i] = __floats2half2_rn(v0, v1);
        }
        uint4* dst = (uint4*)((char*)rh + (size_t)node * 64 + f0 * 2);
        dst[0] = o[0];
        dst[1] = o[1];
    }
}

// ---------------------------------------------------------------------------
// Aggregation 2 + W2 transform + bias2 + log-softmax: one block per bin.
// ---------------------------------------------------------------------------
__global__ __launch_bounds__(256) void agg2_lsm_kernel(const int* __restrict__ binbase,
                                                       const int2* __restrict__ stg,
                                                       const __half* __restrict__ rh,
                                                       const float* __restrict__ W2,
                                                       const float* __restrict__ b2,
                                                       float* __restrict__ out) {
    __shared__ float acc[BIN_NODES * 33];       // 16.9 KB
    __shared__ float W2s[F_HID * F_OUT];        // 5 KB
    const int tid = threadIdx.x;
    const int b   = blockIdx.x;
    for (int i = tid; i < F_HID * F_OUT; i += 256) W2s[i] = W2[i];
    for (int i = tid; i < BIN_NODES * 33; i += 256) acc[i] = 0.f;
    __syncthreads();

    const int start = binbase[b], end = binbase[b + 1];
    const int q  = tid & 7;
    const int q4 = q * 4;
    const unsigned q8 = q * 8;
    const char* tbl = (const char*)rh;

    for (int j0 = start; j0 < end; j0 += 64) {
        const int j1 = j0 + (tid >> 3);
        const int j2 = j1 + 32;
        const bool v1 = j1 < end, v2 = j2 < end;
        int2 p1 = make_int2(0, 0), p2 = make_int2(0, 0);
        uint2 r1 = make_uint2(0, 0), r2 = make_uint2(0, 0);
        if (v1) { p1 = stg[j1]; r1 = *(const uint2*)(tbl + ((unsigned)(p1.x & 0x1FFFF) << 6) + q8); }
        if (v2) { p2 = stg[j2]; r2 = *(const uint2*)(tbl + ((unsigned)(p2.x & 0x1FFFF) << 6) + q8); }
        if (v1) AGG_EDGE(p1, r1);
        if (v2) AGG_EDGE(p2, r2);
    }
    __syncthreads();

    // epilogue: per-node transform + log-softmax; 4 waves x 32 nodes each
    const int wv = tid >> 6, lane = tid & 63;
    const float bb = (lane < F_OUT) ? b2[lane] : 0.f;
    for (int nn = wv; nn < BIN_NODES; nn += 4) {
        const int node = (b << BIN_SHIFT) + nn;
        if (node >= N_NODES) break;
        float val = -INFINITY;
        if (lane < F_OUT) {
            float s = bb;
            #pragma unroll
            for (int k = 0; k < F_HID; ++k)
                s += acc[nn * 33 + k] * W2s[k * F_OUT + lane];
            val = s;
        }
        float m = val;
        for (int off = 32; off; off >>= 1) m = fmaxf(m, __shfl_xor(m, off));
        float ex = (lane < F_OUT) ? expf(val - m) : 0.f;
        for (int off = 32; off; off >>= 1) ex += __shfl_xor(ex, off);
        if (lane < F_OUT) out[(size_t)node * F_OUT + lane] = val - m - logf(ex);
    }
}

// ---------------------------------------------------------------------------
extern "C" void kernel_launch(void* const* d_in, const int* in_sizes, int n_in,
                              void* d_out, int out_size, void* d_ws, size_t ws_size,
                              hipStream_t stream) {
    const float* x  = (const float*)d_in[0];
    const int*   ei = (const int*)d_in[1];    // [2, E] int32: row 0 = src, row 1 = dst
    const float* ew = (const float*)d_in[2];
    const float* W1 = (const float*)d_in[3];
    const float* b1 = (const float*)d_in[4];
    const float* W2 = (const float*)d_in[5];
    const float* b2 = (const float*)d_in[6];
    float* out = (float*)d_out;

    // Workspace layout (16B-aligned):
    //   gcnt    : NBLK*NBINS ints   2.45 MB
    //   pbase   : NBLK*NBINS ints   2.45 MB
    //   bintot  : NBINS ints
    //   binbase : NBINS+1 ints
    //   stg     : E int2           25.6 MB   (lives through both aggregations)
    //   h1h     : N*32 fp16         6.4 MB
    //   rh      : N*32 fp16         6.4 MB
    //   total ~ 43.3 MB
    char* p = (char*)d_ws;
    size_t off = 0;
    auto alloc = [&](size_t bytes) {
        char* r = p + off;
        off += (bytes + 15) & ~(size_t)15;
        return r;
    };
    int*    gcnt    = (int*)   alloc((size_t)NBLK * NBINS * 4);
    int*    pbase   = (int*)   alloc((size_t)NBLK * NBINS * 4);
    int*    bintot  = (int*)   alloc((size_t)NBINS * 4);
    int*    binbase = (int*)   alloc((size_t)(NBINS + 1) * 4);
    int2*   stg     = (int2*)  alloc((size_t)N_EDGES * 8);
    __half* h1h     = (__half*)alloc((size_t)N_NODES * F_HID * 2);
    __half* rh      = (__half*)alloc((size_t)N_NODES * F_HID * 2);

    // --- Partition build (no global atomics, fully deterministic sizes) ---
    binhistA_kernel<<<NBLK, 256, 0, stream>>>(ei, gcnt);
    colscan_kernel<<<NBINS, 256, 0, stream>>>(gcnt, pbase, bintot);
    binscan_kernel<<<1, 1024, 0, stream>>>(bintot, binbase);
    placeA_kernel<<<NBLK, 256, 0, stream>>>(ei, ew, binbase, pbase, stg);

    // --- Layer 1: h1 = x@W1 (fp16 table); r = relu(agg(h1)+b1) (fp16 table) ---
    gemm1_kernel<<<N_NODES / 32, 256, 0, stream>>>(x, W1, h1h);
    agg1_kernel<<<NBINS, 256, 0, stream>>>(binbase, stg, h1h, b1, rh);

    // --- Layer 2: aggregate -> transform -> bias2 -> log-softmax, fused ---
    agg2_lsm_kernel<<<NBINS, 256, 0, stream>>>(binbase, stg, rh, W2, b2, out);
}

// Round 8
// 263.947 us; speedup vs baseline: 5.6051x; 5.6051x over previous
//
#include <hip/hip_runtime.h>
#include <hip/hip_fp16.h>
#include <math.h>

#define N_NODES 100000
#define N_EDGES 3200000
#define F_IN    128
#define F_HID   32
#define F_OUT   40
#define NBINS   ((N_NODES + 255) >> 8)   // 391 coarse bins of 256 nodes
#define EPB     4096                     // edges per block in partition pass A
#define NBLK    ((N_EDGES + EPB - 1) / EPB)

// ---------------------------------------------------------------------------
// GEMM1: h1h[N,32] = fp16(x[N,128] @ W1[128,32])
// ---------------------------------------------------------------------------
__global__ __launch_bounds__(256) void gemm1_kernel(const float* __restrict__ x,
                                                    const float* __restrict__ W,
                                                    __half* __restrict__ h1h) {
    __shared__ float Ws[F_IN * F_HID];     // 16 KB
    __shared__ float Xs[32][F_IN + 4];
    const int tid  = threadIdx.x;
    const int row0 = blockIdx.x * 32;

    for (int i = tid; i < (F_IN * F_HID) / 4; i += 256)
        ((float4*)Ws)[i] = ((const float4*)W)[i];

    for (int i = tid; i < 1024; i += 256) {
        int r = i >> 5;
        int c = i & 31;
        ((float4*)&Xs[r][0])[c] = ((const float4*)x)[(size_t)(row0 + r) * (F_IN / 4) + c];
    }
    __syncthreads();

    const int r  = tid >> 3;
    const int c0 = (tid & 7) * 4;
    float a0 = 0.f, a1 = 0.f, a2 = 0.f, a3 = 0.f;
    for (int k = 0; k < F_IN; ++k) {
        const float xv = Xs[r][k];
        const float* wrow = &Ws[k * F_HID + c0];
        a0 += xv * wrow[0];
        a1 += xv * wrow[1];
        a2 += xv * wrow[2];
        a3 += xv * wrow[3];
    }
    const int row = row0 + r;   // grid exact: 3125*32 == N_NODES
    __half2* o = (__half2*)(h1h + (size_t)row * F_HID + c0);
    o[0] = __floats2half2_rn(a0, a1);
    o[1] = __floats2half2_rn(a2, a3);
}

// ---------------------------------------------------------------------------
// Coarse-bin histogram (391 bins), LDS-aggregated.
// ---------------------------------------------------------------------------
__global__ __launch_bounds__(256) void binhist_kernel(const int* __restrict__ ei,
                                                      int* __restrict__ bincnt) {
    __shared__ int lc[NBINS];
    for (int i = threadIdx.x; i < NBINS; i += 256) lc[i] = 0;
    __syncthreads();
    const int stride = gridDim.x * 256;
    for (int e = blockIdx.x * 256 + threadIdx.x; e < N_EDGES; e += stride)
        atomicAdd(&lc[ei[N_EDGES + e] >> 8], 1);
    __syncthreads();
    for (int i = threadIdx.x; i < NBINS; i += 256)
        if (lc[i]) atomicAdd(&bincnt[i], lc[i]);
}

// ---------------------------------------------------------------------------
// Scan over 391 bin counts -> binbase[0..NBINS], cursor, offs[N]=E.
// ---------------------------------------------------------------------------
__global__ __launch_bounds__(512) void binscan_kernel(const int* __restrict__ bincnt,
                                                      int* __restrict__ binbase,
                                                      int* __restrict__ cursor,
                                                      int* __restrict__ offs) {
    __shared__ int s[512];
    const int t = threadIdx.x;
    const int v = (t < NBINS) ? bincnt[t] : 0;
    s[t] = v;
    __syncthreads();
    for (int off = 1; off < 512; off <<= 1) {
        int u = (t >= off) ? s[t - off] : 0;
        __syncthreads();
        s[t] += u;
        __syncthreads();
    }
    const int excl = s[t] - v;
    if (t <= NBINS) binbase[t] = excl;
    if (t < NBINS)  cursor[t]  = excl;
    if (t == 0)     offs[N_NODES] = N_EDGES;
}

// ---------------------------------------------------------------------------
// Pass A (v2): LDS-staged multisplit. Count (4-deep preload) -> in-LDS
// exclusive scan -> one global cursor reserve per bin -> rank pass places
// entries bin-sorted into a 32KB LDS staging buffer -> write-out streams
// them to global in bin order (consecutive threads -> consecutive addrs,
// no 64B-line write amplification). Staged entry:
//   .x = src(17b) | dst_low8 << 17, .y = weight fp32 bits.
// ---------------------------------------------------------------------------
__global__ __launch_bounds__(256) void partA_kernel(const int* __restrict__ ei,
                                                    const float* __restrict__ ew,
                                                    int* __restrict__ cursor,
                                                    int2* __restrict__ stg) {
    __shared__ int lhist[512];
    __shared__ int lscan[512];
    __shared__ int lcur[512];
    __shared__ int lbase[512];
    __shared__ int stmp[256];
    __shared__ int2 lstg[EPB];                 // 32 KB
    __shared__ unsigned short lbin[EPB];       // 8 KB
    const int tid = threadIdx.x;
    const int e0  = blockIdx.x * EPB;
    const int tot = min(EPB, N_EDGES - e0);

    lhist[tid] = 0; lhist[tid + 256] = 0;
    __syncthreads();

    // --- count, 4-deep preload ---
    for (int base = 0; base < EPB; base += 1024) {
        int d0 = -1, d1 = -1, d2 = -1, d3 = -1;
        const int e = e0 + base + tid;
        if (e < N_EDGES)       d0 = ei[N_EDGES + e] >> 8;
        if (e + 256 < N_EDGES) d1 = ei[N_EDGES + e + 256] >> 8;
        if (e + 512 < N_EDGES) d2 = ei[N_EDGES + e + 512] >> 8;
        if (e + 768 < N_EDGES) d3 = ei[N_EDGES + e + 768] >> 8;
        if (d0 >= 0) atomicAdd(&lhist[d0], 1);
        if (d1 >= 0) atomicAdd(&lhist[d1], 1);
        if (d2 >= 0) atomicAdd(&lhist[d2], 1);
        if (d3 >= 0) atomicAdd(&lhist[d3], 1);
    }
    __syncthreads();

    // --- exclusive scan of 512 (each thread owns slots 2t, 2t+1) ---
    const int ca = lhist[2 * tid];
    const int cb = lhist[2 * tid + 1];
    const int pair = ca + cb;
    stmp[tid] = pair;
    __syncthreads();
    for (int off = 1; off < 256; off <<= 1) {
        int u = (tid >= off) ? stmp[tid - off] : 0;
        __syncthreads();
        stmp[tid] += u;
        __syncthreads();
    }
    const int pexcl = stmp[tid] - pair;
    lscan[2 * tid]     = pexcl;
    lscan[2 * tid + 1] = pexcl + ca;
    lcur[2 * tid]      = pexcl;
    lcur[2 * tid + 1]  = pexcl + ca;
    __syncthreads();

    // --- reserve global ranges (one atomic per non-empty bin) ---
    for (int b = tid; b < NBINS; b += 256) {
        const int c = lhist[b];
        lbase[b] = c ? atomicAdd(&cursor[b], c) : 0;
    }
    __syncthreads();

    // --- rank pass: place bin-sorted into LDS, 4-deep preload ---
    for (int base = 0; base < EPB; base += 1024) {
        int s0 = 0, s1 = 0, s2 = 0, s3 = 0;
        int d0 = -1, d1 = -1, d2 = -1, d3 = -1;
        float w0 = 0.f, w1 = 0.f, w2 = 0.f, w3 = 0.f;
        const int e = e0 + base + tid;
        if (e < N_EDGES)       { s0 = ei[e];       d0 = ei[N_EDGES + e];       w0 = ew[e]; }
        if (e + 256 < N_EDGES) { s1 = ei[e + 256]; d1 = ei[N_EDGES + e + 256]; w1 = ew[e + 256]; }
        if (e + 512 < N_EDGES) { s2 = ei[e + 512]; d2 = ei[N_EDGES + e + 512]; w2 = ew[e + 512]; }
        if (e + 768 < N_EDGES) { s3 = ei[e + 768]; d3 = ei[N_EDGES + e + 768]; w3 = ew[e + 768]; }
        if (d0 >= 0) {
            const int b = d0 >> 8;
            const int p = atomicAdd(&lcur[b], 1);
            lstg[p] = make_int2(s0 | ((d0 & 255) << 17), __float_as_int(w0));
            lbin[p] = (unsigned short)b;
        }
        if (d1 >= 0) {
            const int b = d1 >> 8;
            const int p = atomicAdd(&lcur[b], 1);
            lstg[p] = make_int2(s1 | ((d1 & 255) << 17), __float_as_int(w1));
            lbin[p] = (unsigned short)b;
        }
        if (d2 >= 0) {
            const int b = d2 >> 8;
            const int p = atomicAdd(&lcur[b], 1);
            lstg[p] = make_int2(s2 | ((d2 & 255) << 17), __float_as_int(w2));
            lbin[p] = (unsigned short)b;
        }
        if (d3 >= 0) {
            const int b = d3 >> 8;
            const int p = atomicAdd(&lcur[b], 1);
            lstg[p] = make_int2(s3 | ((d3 & 255) << 17), __float_as_int(w3));
            lbin[p] = (unsigned short)b;
        }
    }
    __syncthreads();

    // --- write-out: bin-sorted -> bursty near-sequential global stores ---
    for (int i = tid; i < tot; i += 256) {
        const int b = lbin[i];
        stg[lbase[b] + (i - lscan[b])] = lstg[i];
    }
}

// ---------------------------------------------------------------------------
// Pass B: one block per bin. In-LDS per-node count + scan (writes offs),
// then place 4-byte packed entries: src(17b) | fp16bits(w) << 17.
// (w in [0,1] -> half bits <= 0x3C00 < 2^15, fits the 15-bit field.)
// ---------------------------------------------------------------------------
__global__ __launch_bounds__(256) void partB_kernel(const int* __restrict__ binbase,
                                                    const int2* __restrict__ stg,
                                                    int* __restrict__ offs,
                                                    int* __restrict__ bkt) {
    __shared__ int lcnt[256];
    __shared__ int lsc[256];
    const int tid   = threadIdx.x;
    const int b     = blockIdx.x;
    const int start = binbase[b];
    const int end   = binbase[b + 1];

    lcnt[tid] = 0;
    __syncthreads();
    for (int j = start + tid; j < end; j += 256)
        atomicAdd(&lcnt[(stg[j].x >> 17) & 255], 1);
    __syncthreads();

    const int v = lcnt[tid];
    lsc[tid] = v;
    __syncthreads();
    for (int off = 1; off < 256; off <<= 1) {
        int u = (tid >= off) ? lsc[tid - off] : 0;
        __syncthreads();
        lsc[tid] += u;
        __syncthreads();
    }
    const int base = start + (lsc[tid] - v);
    const int node = (b << 8) + tid;
    if (node < N_NODES) offs[node] = base;
    __syncthreads();
    lcnt[tid] = base;          // reuse as cursor
    __syncthreads();

    for (int j = start + tid; j < end; j += 256) {
        const int2 p = stg[j];
        const int dlow = (p.x >> 17) & 255;
        const unsigned hb = __half_as_ushort(__float2half(__int_as_float(p.y)));
        const int pos = atomicAdd(&lcnt[dlow], 1);
        bkt[pos] = (p.x & 0x1FFFF) | ((int)hb << 17);
    }
}

// ---------------------------------------------------------------------------
// Shared gather core: 8 edge-groups x 8 lanes; each lane holds an 8B (4-feat)
// row fragment; 2-deep unroll = 16 edges in flight per wave.
// ---------------------------------------------------------------------------
#define GATHER_EDGE(P, A0, A1, A2, A3)                                          \
    {                                                                           \
        const float wgt = __half2float(__ushort_as_half(                        \
            (unsigned short)((unsigned)(P) >> 17)));                            \
        const uint2 rv = *(const uint2*)(tbl + (((unsigned)((P) & 0x1FFFF)) << 6) + sub8); \
        float2 v;                                                               \
        v = __half22float2(*(const __half2*)&rv.x);                             \
        A0 += v.x * wgt; A1 += v.y * wgt;                                       \
        v = __half22float2(*(const __half2*)&rv.y);                             \
        A2 += v.x * wgt; A3 += v.y * wgt;                                       \
    }

// ---------------------------------------------------------------------------
// Gather 1 + bias1 + ReLU: rh[n] = fp16(relu(sum_e w_e * h1h[src_e] + b1))
// ---------------------------------------------------------------------------
__global__ __launch_bounds__(256) void gather1_kernel(const int* __restrict__ offs,
                                                      const int* __restrict__ bkt,
                                                      const __half* __restrict__ h1h,
                                                      const float* __restrict__ b1,
                                                      __half* __restrict__ rh) {
    const int wave = threadIdx.x >> 6, lane = threadIdx.x & 63;
    const int node = blockIdx.x * 4 + wave;          // grid exact: 25000*4
    const int g    = lane >> 3;
    const int sub  = lane & 7;
    const unsigned sub8 = sub * 8;
    const char* tbl = (const char*)h1h;

    int j = offs[node] + g;
    const int jend = offs[node + 1];
    float a0 = 0.f, a1 = 0.f, a2 = 0.f, a3 = 0.f;
    float c0 = 0.f, c1 = 0.f, c2 = 0.f, c3 = 0.f;
    for (; j + 8 < jend; j += 16) {
        const int p0 = bkt[j];
        const int p1 = bkt[j + 8];
        GATHER_EDGE(p0, a0, a1, a2, a3);
        GATHER_EDGE(p1, c0, c1, c2, c3);
    }
    if (j < jend) {
        const int p = bkt[j];
        GATHER_EDGE(p, a0, a1, a2, a3);
    }
    a0 += c0; a1 += c1; a2 += c2; a3 += c3;
    #pragma unroll
    for (int off = 8; off < 64; off <<= 1) {
        a0 += __shfl_xor(a0, off);
        a1 += __shfl_xor(a1, off);
        a2 += __shfl_xor(a2, off);
        a3 += __shfl_xor(a3, off);
    }
    if (g == 0) {
        const float4 bb = ((const float4*)b1)[sub];
        a0 = fmaxf(a0 + bb.x, 0.f);
        a1 = fmaxf(a1 + bb.y, 0.f);
        a2 = fmaxf(a2 + bb.z, 0.f);
        a3 = fmaxf(a3 + bb.w, 0.f);
        uint2 o;
        *(__half2*)&o.x = __floats2half2_rn(a0, a1);
        *(__half2*)&o.y = __floats2half2_rn(a2, a3);
        *(uint2*)((char*)rh + (size_t)node * 64 + sub8) = o;
    }
}

// ---------------------------------------------------------------------------
// Gather 2 + GEMM2 + bias2 + log-softmax, all fused. One wave per node.
// ---------------------------------------------------------------------------
__global__ __launch_bounds__(256) void gather2_lsm_kernel(const int* __restrict__ offs,
                                                          const int* __restrict__ bkt,
                                                          const __half* __restrict__ rh,
                                                          const float* __restrict__ W2,
                                                          const float* __restrict__ b2,
                                                          float* __restrict__ out) {
    __shared__ float W2s[F_HID * F_OUT];   // 5 KB
    __shared__ float rb[4][F_HID];
    const int tid = threadIdx.x;
    for (int i = tid; i < F_HID * F_OUT; i += 256) W2s[i] = W2[i];

    const int wave = tid >> 6, lane = tid & 63;
    const int node = blockIdx.x * 4 + wave;          // grid exact
    const int g    = lane >> 3;
    const int sub  = lane & 7;
    const unsigned sub8 = sub * 8;
    const char* tbl = (const char*)rh;

    int j = offs[node] + g;
    const int jend = offs[node + 1];
    float a0 = 0.f, a1 = 0.f, a2 = 0.f, a3 = 0.f;
    float c0 = 0.f, c1 = 0.f, c2 = 0.f, c3 = 0.f;
    for (; j + 8 < jend; j += 16) {
        const int p0 = bkt[j];
        const int p1 = bkt[j + 8];
        GATHER_EDGE(p0, a0, a1, a2, a3);
        GATHER_EDGE(p1, c0, c1, c2, c3);
    }
    if (j < jend) {
        const int p = bkt[j];
        GATHER_EDGE(p, a0, a1, a2, a3);
    }
    a0 += c0; a1 += c1; a2 += c2; a3 += c3;
    #pragma unroll
    for (int off = 8; off < 64; off <<= 1) {
        a0 += __shfl_xor(a0, off);
        a1 += __shfl_xor(a1, off);
        a2 += __shfl_xor(a2, off);
        a3 += __shfl_xor(a3, off);
    }
    if (g == 0)
        ((float4*)&rb[wave][0])[sub] = make_float4(a0, a1, a2, a3);
    __syncthreads();

    float val = -INFINITY;
    if (lane < F_OUT) {
        float acc = b2[lane];
        #pragma unroll
        for (int k = 0; k < F_HID; ++k)
            acc += rb[wave][k] * W2s[k * F_OUT + lane];
        val = acc;
    }
    float m = val;
    for (int off = 32; off; off >>= 1) m = fmaxf(m, __shfl_xor(m, off));
    float ex = (lane < F_OUT) ? expf(val - m) : 0.f;
    for (int off = 32; off; off >>= 1) ex += __shfl_xor(ex, off);
    if (lane < F_OUT) out[(size_t)node * F_OUT + lane] = val - m - logf(ex);
}

// ---------------------------------------------------------------------------
extern "C" void kernel_launch(void* const* d_in, const int* in_sizes, int n_in,
                              void* d_out, int out_size, void* d_ws, size_t ws_size,
                              hipStream_t stream) {
    const float* x  = (const float*)d_in[0];
    const int*   ei = (const int*)d_in[1];    // [2, E] int32: row 0 = src, row 1 = dst
    const float* ew = (const float*)d_in[2];
    const float* W1 = (const float*)d_in[3];
    const float* b1 = (const float*)d_in[4];
    const float* W2 = (const float*)d_in[5];
    const float* b2 = (const float*)d_in[6];
    float* out = (float*)d_out;

    // Workspace layout (16B-aligned):
    //   bincnt  : NBINS ints
    //   binbase : NBINS+1 ints
    //   cursor  : NBINS ints
    //   offs    : N+1 ints          0.4 MB
    //   bkt     : E ints           12.8 MB
    //   union   : stg[E] int2 (25.6 MB, build only)  /  h1h + rh fp16 (12.8 MB)
    char* p = (char*)d_ws;
    size_t off = 0;
    auto alloc = [&](size_t bytes) {
        char* r = p + off;
        off += (bytes + 15) & ~(size_t)15;
        return r;
    };
    int*   bincnt  = (int*)  alloc((size_t)NBINS * 4);
    int*   binbase = (int*)  alloc((size_t)(NBINS + 1) * 4);
    int*   cursor  = (int*)  alloc((size_t)NBINS * 4);
    int*   offs    = (int*)  alloc((size_t)(N_NODES + 1) * 4);
    int*   bkt     = (int*)  alloc((size_t)N_EDGES * 4);
    char*  uni     = (char*) alloc((size_t)N_EDGES * 8);   // stg is the larger member
    int2*  stg     = (int2*)uni;
    __half* h1h    = (__half*)uni;
    __half* rh     = h1h + (size_t)N_NODES * F_HID;

    // --- CSR build (dst-major buckets, packed 4B entries) ---
    hipMemsetAsync(bincnt, 0, (size_t)NBINS * 4, stream);
    binhist_kernel<<<1024, 256, 0, stream>>>(ei, bincnt);
    binscan_kernel<<<1, 512, 0, stream>>>(bincnt, binbase, cursor, offs);
    partA_kernel<<<NBLK, 256, 0, stream>>>(ei, ew, cursor, stg);
    partB_kernel<<<NBINS, 256, 0, stream>>>(binbase, stg, offs, bkt);

    // --- Layer 1: h1 = x@W1 (fp16 table), r = relu(agg(h1)+b1) (fp16 table) ---
    gemm1_kernel<<<N_NODES / 32, 256, 0, stream>>>(x, W1, h1h);
    gather1_kernel<<<N_NODES / 4, 256, 0, stream>>>(offs, bkt, h1h, b1, rh);

    // --- Layer 2 (aggregate-then-transform) + bias2 + log-softmax, fused ---
    gather2_lsm_kernel<<<N_NODES / 4, 256, 0, stream>>>(offs, bkt, rh, W2, b2, out);
}